// Round 4
// baseline (145.522 us; speedup 1.0000x reference)
//
#include <hip/hip_runtime.h>

#define N_NODES 100000
#define N_EDGES 1600000
#define D_FEAT 64

// ---------------------------------------------------------------------------
// Kernel 1: build CSR row_ptr from the sorted target_index.
// ---------------------------------------------------------------------------
__global__ __launch_bounds__(256) void build_row_ptr(
    const int* __restrict__ tgt, int* __restrict__ row_ptr)
{
    int e = blockIdx.x * blockDim.x + threadIdx.x;
    if (e >= N_EDGES) return;
    int cur = tgt[e];
    int lo  = (e == 0) ? 0 : tgt[e - 1] + 1;
    for (int n = lo; n <= cur; ++n) row_ptr[n] = e;
    if (e == N_EDGES - 1) {
        for (int n = cur + 1; n <= N_NODES; ++n) row_ptr[n] = N_EDGES;
    }
}

// ---------------------------------------------------------------------------
// Kernel 2: segmented gather-sum.
// 16-lane group = 4 consecutive nodes; lane f owns float4 f of the feature row.
// Group streams its union edge range with 3-phase software pipeline:
//   src/ev prefetched 8 edges ahead, x-gather issued 4 edges ahead.
// Row boundaries -> plain store flush (no atomics, empty nodes store 0).
// ---------------------------------------------------------------------------
__global__ __launch_bounds__(256) void gather_sum(
    const float4* __restrict__ x4,        // [N_NODES, 16] float4
    const float*  __restrict__ ev,        // [N_EDGES]
    const int*    __restrict__ src,       // [N_EDGES]
    const int*    __restrict__ row_ptr,   // [N_NODES+1]
    float4*       __restrict__ out4)      // [N_NODES, 16] float4
{
    const int gid = (blockIdx.x * 256 + threadIdx.x) >> 4;
    if (gid >= N_NODES / 4) return;
    const int f  = threadIdx.x & 15;
    const int n0 = gid * 4;

    const int rp0 = row_ptr[n0];
    const int rp1 = row_ptr[n0 + 1];
    const int rp2 = row_ptr[n0 + 2];
    const int rp3 = row_ptr[n0 + 3];
    const int rp4 = row_ptr[n0 + 4];

    const int e0   = rp0;
    const int eend = rp4;
    const int len  = eend - e0;

    float4 acc = make_float4(0.f, 0.f, 0.f, 0.f);
    int node  = n0;
    int bound = rp1;

    if (len > 0) {
        const int emax = eend - 1;

// clamped src/ev fetch: address clamped in-range, weight forced 0 past end
#define LOADSW(EIDX, S, W) do { int _e = (EIDX); int _ec = _e < emax ? _e : emax; \
        S = src[_ec]; float _w = ev[_ec]; W = (_e < eend) ? _w : 0.0f; } while (0)

// flush completed nodes (handles empties), then accumulate one edge
#define CONSUME1(EIDX, W, X) do { int _ce = (EIDX); \
        while (_ce < eend && _ce >= bound) { \
            out4[node * 16 + f] = acc; \
            acc = make_float4(0.f, 0.f, 0.f, 0.f); \
            ++node; int _d = node - n0; \
            bound = (_d == 1) ? rp2 : (_d == 2) ? rp3 : rp4; } \
        acc.x = fmaf((W), (X).x, acc.x); \
        acc.y = fmaf((W), (X).y, acc.y); \
        acc.z = fmaf((W), (X).z, acc.z); \
        acc.w = fmaf((W), (X).w, acc.w); } while (0)

        int    sA0,sA1,sA2,sA3, sB0,sB1,sB2,sB3, sC0,sC1,sC2,sC3;
        float  wA0,wA1,wA2,wA3, wB0,wB1,wB2,wB3, wC0,wC1,wC2,wC3;
        float4 xA0,xA1,xA2,xA3, xB0,xB1,xB2,xB3, xC0,xC1,xC2,xC3;

        // prologue: s/w for chunk0 (A) and chunk1 (B); issue x for chunk0
        LOADSW(e0 + 0, sA0, wA0); LOADSW(e0 + 1, sA1, wA1);
        LOADSW(e0 + 2, sA2, wA2); LOADSW(e0 + 3, sA3, wA3);
        LOADSW(e0 + 4, sB0, wB0); LOADSW(e0 + 5, sB1, wB1);
        LOADSW(e0 + 6, sB2, wB2); LOADSW(e0 + 7, sB3, wB3);
        xA0 = x4[sA0 * 16 + f]; xA1 = x4[sA1 * 16 + f];
        xA2 = x4[sA2 * 16 + f]; xA3 = x4[sA3 * 16 + f];

        for (int i = 0; i < len; i += 12) {
            // ---- body0: prefetch chunk i+8 -> C; issue x(chunk i+4) from B;
            //             consume chunk i (A)
            LOADSW(e0 + i + 8,  sC0, wC0); LOADSW(e0 + i + 9,  sC1, wC1);
            LOADSW(e0 + i + 10, sC2, wC2); LOADSW(e0 + i + 11, sC3, wC3);
            xB0 = x4[sB0 * 16 + f]; xB1 = x4[sB1 * 16 + f];
            xB2 = x4[sB2 * 16 + f]; xB3 = x4[sB3 * 16 + f];
            CONSUME1(e0 + i + 0, wA0, xA0); CONSUME1(e0 + i + 1, wA1, xA1);
            CONSUME1(e0 + i + 2, wA2, xA2); CONSUME1(e0 + i + 3, wA3, xA3);

            // ---- body1: prefetch chunk i+12 -> A; issue x(chunk i+8) from C;
            //             consume chunk i+4 (B)
            LOADSW(e0 + i + 12, sA0, wA0); LOADSW(e0 + i + 13, sA1, wA1);
            LOADSW(e0 + i + 14, sA2, wA2); LOADSW(e0 + i + 15, sA3, wA3);
            xC0 = x4[sC0 * 16 + f]; xC1 = x4[sC1 * 16 + f];
            xC2 = x4[sC2 * 16 + f]; xC3 = x4[sC3 * 16 + f];
            CONSUME1(e0 + i + 4, wB0, xB0); CONSUME1(e0 + i + 5, wB1, xB1);
            CONSUME1(e0 + i + 6, wB2, xB2); CONSUME1(e0 + i + 7, wB3, xB3);

            // ---- body2: prefetch chunk i+16 -> B; issue x(chunk i+12) from A;
            //             consume chunk i+8 (C)
            LOADSW(e0 + i + 16, sB0, wB0); LOADSW(e0 + i + 17, sB1, wB1);
            LOADSW(e0 + i + 18, sB2, wB2); LOADSW(e0 + i + 19, sB3, wB3);
            xA0 = x4[sA0 * 16 + f]; xA1 = x4[sA1 * 16 + f];
            xA2 = x4[sA2 * 16 + f]; xA3 = x4[sA3 * 16 + f];
            CONSUME1(e0 + i + 8,  wC0, xC0); CONSUME1(e0 + i + 9,  wC1, xC1);
            CONSUME1(e0 + i + 10, wC2, xC2); CONSUME1(e0 + i + 11, wC3, xC3);
        }
#undef LOADSW
#undef CONSUME1
    }

    // final flushes: current node's acc, then zeros for any remaining nodes
    while (node < n0 + 4) {
        out4[node * 16 + f] = acc;
        acc = make_float4(0.f, 0.f, 0.f, 0.f);
        ++node;
    }
}

extern "C" void kernel_launch(void* const* d_in, const int* in_sizes, int n_in,
                              void* d_out, int out_size, void* d_ws, size_t ws_size,
                              hipStream_t stream) {
    const float* x            = (const float*)d_in[0];
    const float* edge_values  = (const float*)d_in[1];
    const int*   target_index = (const int*)d_in[2];
    const int*   source_index = (const int*)d_in[3];
    float*       out          = (float*)d_out;
    int*         row_ptr      = (int*)d_ws;   // (N_NODES+1) * 4 bytes

    build_row_ptr<<<(N_EDGES + 255) / 256, 256, 0, stream>>>(target_index, row_ptr);

    const int n_groups = N_NODES / 4;            // 25000
    const int n_blocks = (n_groups + 15) / 16;   // 16 groups per 256-thread block
    gather_sum<<<n_blocks, 256, 0, stream>>>(
        (const float4*)x, edge_values, source_index, row_ptr, (float4*)out);
}

// Round 5
// 134.475 us; speedup vs baseline: 1.0821x; 1.0821x over previous
//
#include <hip/hip_runtime.h>
#include <hip/hip_fp16.h>

#define N_NODES 100000
#define N_EDGES 1600000
#define D_FEAT 64

typedef __attribute__((ext_vector_type(4))) _Float16 half4v;

// ---------------------------------------------------------------------------
// Prep (fused): part A converts x (fp32) -> xh (fp16, 128B rows);
//               part B builds CSR row_ptr from sorted target_index.
// ---------------------------------------------------------------------------
__global__ __launch_bounds__(256) void prep_kernel(
    const float4* __restrict__ x4,   // [N_NODES*16]
    const int*    __restrict__ tgt,  // [N_EDGES] sorted
    half4v*       __restrict__ xh,   // [N_NODES*16]
    int*          __restrict__ row_ptr,
    int conv_blocks)
{
    const int bid = blockIdx.x;
    if (bid < conv_blocks) {
        int i = bid * 256 + threadIdx.x;       // one float4 -> one half4
        if (i < N_NODES * 16) {
            float4 v = x4[i];
            half4v h;
            h.x = (_Float16)v.x; h.y = (_Float16)v.y;
            h.z = (_Float16)v.z; h.w = (_Float16)v.w;
            xh[i] = h;
        }
    } else {
        int e = (bid - conv_blocks) * 256 + threadIdx.x;
        if (e >= N_EDGES) return;
        int cur = tgt[e];
        int lo  = (e == 0) ? 0 : tgt[e - 1] + 1;
        for (int n = lo; n <= cur; ++n) row_ptr[n] = e;
        if (e == N_EDGES - 1) {
            for (int n = cur + 1; n <= N_NODES; ++n) row_ptr[n] = N_EDGES;
        }
    }
}

// Standalone row_ptr build (fallback path)
__global__ __launch_bounds__(256) void build_row_ptr(
    const int* __restrict__ tgt, int* __restrict__ row_ptr)
{
    int e = blockIdx.x * blockDim.x + threadIdx.x;
    if (e >= N_EDGES) return;
    int cur = tgt[e];
    int lo  = (e == 0) ? 0 : tgt[e - 1] + 1;
    for (int n = lo; n <= cur; ++n) row_ptr[n] = e;
    if (e == N_EDGES - 1) {
        for (int n = cur + 1; n <= N_NODES; ++n) row_ptr[n] = N_EDGES;
    }
}

// ---------------------------------------------------------------------------
// Gather-sum over fp16 rows. One wave per node; 4 edge-groups x 16 lanes;
// lane owns 4 features (8B half4 per edge). 2-stage pipeline, 8 edges in
// flight; next-8 src/ev prefetched before the x-wait. fp32 accumulate.
// ---------------------------------------------------------------------------
__global__ __launch_bounds__(256) void gather_sum_h(
    const half4v* __restrict__ xh,       // [N_NODES, 16] half4
    const float*  __restrict__ ev,
    const int*    __restrict__ src,
    const int*    __restrict__ row_ptr,
    float4*       __restrict__ out4)     // [N_NODES, 16] float4
{
    const int node = blockIdx.x * 4 + (threadIdx.x >> 6);
    if (node >= N_NODES) return;
    const int lane = threadIdx.x & 63;
    const int g    = lane >> 4;
    const int f    = lane & 15;

    const int start = row_ptr[node];
    const int end   = row_ptr[node + 1];

    float4 acc = make_float4(0.f, 0.f, 0.f, 0.f);

    if (start < end) {
        int  ea = start + g, eb = start + 4 + g;
        bool va = ea < end,  vb = eb < end;
        int  esa = va ? ea : start, esb = vb ? eb : start;
        float wa = va ? ev[esa] : 0.0f;
        float wb = vb ? ev[esb] : 0.0f;
        int   sa = src[esa];
        int   sb = src[esb];

        for (int e0 = start; e0 < end; e0 += 8) {
            const half4v xa = xh[sa * 16 + f];
            const half4v xb = xh[sb * 16 + f];
            const float cwa = wa, cwb = wb;

            {
                int  na = e0 + 8 + g, nb = e0 + 12 + g;
                bool vna = na < end,  vnb = nb < end;
                int  nsa = vna ? na : start, nsb = vnb ? nb : start;
                wa = vna ? ev[nsa] : 0.0f;
                wb = vnb ? ev[nsb] : 0.0f;
                sa = src[nsa];
                sb = src[nsb];
            }

            acc.x = fmaf(cwa, (float)xa.x, acc.x);
            acc.y = fmaf(cwa, (float)xa.y, acc.y);
            acc.z = fmaf(cwa, (float)xa.z, acc.z);
            acc.w = fmaf(cwa, (float)xa.w, acc.w);
            acc.x = fmaf(cwb, (float)xb.x, acc.x);
            acc.y = fmaf(cwb, (float)xb.y, acc.y);
            acc.z = fmaf(cwb, (float)xb.z, acc.z);
            acc.w = fmaf(cwb, (float)xb.w, acc.w);
        }
    }

    acc.x += __shfl_xor(acc.x, 16, 64);
    acc.y += __shfl_xor(acc.y, 16, 64);
    acc.z += __shfl_xor(acc.z, 16, 64);
    acc.w += __shfl_xor(acc.w, 16, 64);
    acc.x += __shfl_xor(acc.x, 32, 64);
    acc.y += __shfl_xor(acc.y, 32, 64);
    acc.z += __shfl_xor(acc.z, 32, 64);
    acc.w += __shfl_xor(acc.w, 32, 64);

    if (g == 0) out4[node * 16 + f] = acc;
}

// fp32 fallback gather (R3 structure) if ws can't hold xh
__global__ __launch_bounds__(256) void gather_sum_f32(
    const float4* __restrict__ x4,
    const float*  __restrict__ ev,
    const int*    __restrict__ src,
    const int*    __restrict__ row_ptr,
    float4*       __restrict__ out4)
{
    const int node = blockIdx.x * 4 + (threadIdx.x >> 6);
    if (node >= N_NODES) return;
    const int lane = threadIdx.x & 63;
    const int g    = lane >> 4;
    const int f    = lane & 15;

    const int start = row_ptr[node];
    const int end   = row_ptr[node + 1];

    float4 acc = make_float4(0.f, 0.f, 0.f, 0.f);
    if (start < end) {
        int  ea = start + g, eb = start + 4 + g;
        bool va = ea < end,  vb = eb < end;
        int  esa = va ? ea : start, esb = vb ? eb : start;
        float wa = va ? ev[esa] : 0.0f;
        float wb = vb ? ev[esb] : 0.0f;
        int   sa = src[esa];
        int   sb = src[esb];

        for (int e0 = start; e0 < end; e0 += 8) {
            const float4 xa = x4[sa * 16 + f];
            const float4 xb = x4[sb * 16 + f];
            const float cwa = wa, cwb = wb;
            {
                int  na = e0 + 8 + g, nb = e0 + 12 + g;
                bool vna = na < end,  vnb = nb < end;
                int  nsa = vna ? na : start, nsb = vnb ? nb : start;
                wa = vna ? ev[nsa] : 0.0f;
                wb = vnb ? ev[nsb] : 0.0f;
                sa = src[nsa];
                sb = src[nsb];
            }
            acc.x = fmaf(cwa, xa.x, acc.x);
            acc.y = fmaf(cwa, xa.y, acc.y);
            acc.z = fmaf(cwa, xa.z, acc.z);
            acc.w = fmaf(cwa, xa.w, acc.w);
            acc.x = fmaf(cwb, xb.x, acc.x);
            acc.y = fmaf(cwb, xb.y, acc.y);
            acc.z = fmaf(cwb, xb.z, acc.z);
            acc.w = fmaf(cwb, xb.w, acc.w);
        }
    }
    acc.x += __shfl_xor(acc.x, 16, 64);
    acc.y += __shfl_xor(acc.y, 16, 64);
    acc.z += __shfl_xor(acc.z, 16, 64);
    acc.w += __shfl_xor(acc.w, 16, 64);
    acc.x += __shfl_xor(acc.x, 32, 64);
    acc.y += __shfl_xor(acc.y, 32, 64);
    acc.z += __shfl_xor(acc.z, 32, 64);
    acc.w += __shfl_xor(acc.w, 32, 64);
    if (g == 0) out4[node * 16 + f] = acc;
}

extern "C" void kernel_launch(void* const* d_in, const int* in_sizes, int n_in,
                              void* d_out, int out_size, void* d_ws, size_t ws_size,
                              hipStream_t stream) {
    const float* x            = (const float*)d_in[0];
    const float* edge_values  = (const float*)d_in[1];
    const int*   target_index = (const int*)d_in[2];
    const int*   source_index = (const int*)d_in[3];
    float*       out          = (float*)d_out;

    const size_t rp_bytes = (size_t)(N_NODES + 1) * sizeof(int);
    const size_t xh_off   = (rp_bytes + 511) & ~(size_t)511;
    const size_t xh_bytes = (size_t)N_NODES * D_FEAT * sizeof(_Float16); // 12.8 MB
    const size_t need     = xh_off + xh_bytes;

    int* row_ptr = (int*)d_ws;

    if (ws_size >= need) {
        half4v* xh = (half4v*)((char*)d_ws + xh_off);
        const int conv_blocks = (N_NODES * 16 + 255) / 256;          // 6250
        const int rp_blocks   = (N_EDGES + 255) / 256;               // 6250
        prep_kernel<<<conv_blocks + rp_blocks, 256, 0, stream>>>(
            (const float4*)x, target_index, xh, row_ptr, conv_blocks);

        gather_sum_h<<<(N_NODES + 3) / 4, 256, 0, stream>>>(
            xh, edge_values, source_index, row_ptr, (float4*)out);
    } else {
        build_row_ptr<<<(N_EDGES + 255) / 256, 256, 0, stream>>>(target_index, row_ptr);
        gather_sum_f32<<<(N_NODES + 3) / 4, 256, 0, stream>>>(
            (const float4*)x, edge_values, source_index, row_ptr, (float4*)out);
    }
}

// Round 6
// 127.498 us; speedup vs baseline: 1.1414x; 1.0547x over previous
//
#include <hip/hip_runtime.h>
#include <hip/hip_fp16.h>

#define N_NODES 100000
#define N_EDGES 1600000
#define D_FEAT 64

typedef __attribute__((ext_vector_type(4))) _Float16 half4v;

// ---------------------------------------------------------------------------
// Prep (fused): part A converts x (fp32) -> xh (fp16, 128B rows);
//               part B builds CSR row_ptr from sorted target_index.
// ---------------------------------------------------------------------------
__global__ __launch_bounds__(256) void prep_kernel(
    const float4* __restrict__ x4,   // [N_NODES*16]
    const int*    __restrict__ tgt,  // [N_EDGES] sorted
    half4v*       __restrict__ xh,   // [N_NODES*16]
    int*          __restrict__ row_ptr,
    int conv_blocks)
{
    const int bid = blockIdx.x;
    if (bid < conv_blocks) {
        int i = bid * 256 + threadIdx.x;       // one float4 -> one half4
        if (i < N_NODES * 16) {
            float4 v = x4[i];
            half4v h;
            h.x = (_Float16)v.x; h.y = (_Float16)v.y;
            h.z = (_Float16)v.z; h.w = (_Float16)v.w;
            xh[i] = h;
        }
    } else {
        int e = (bid - conv_blocks) * 256 + threadIdx.x;
        if (e >= N_EDGES) return;
        int cur = tgt[e];
        int lo  = (e == 0) ? 0 : tgt[e - 1] + 1;
        for (int n = lo; n <= cur; ++n) row_ptr[n] = e;
        if (e == N_EDGES - 1) {
            for (int n = cur + 1; n <= N_NODES; ++n) row_ptr[n] = N_EDGES;
        }
    }
}

// Standalone row_ptr build (fallback path)
__global__ __launch_bounds__(256) void build_row_ptr(
    const int* __restrict__ tgt, int* __restrict__ row_ptr)
{
    int e = blockIdx.x * blockDim.x + threadIdx.x;
    if (e >= N_EDGES) return;
    int cur = tgt[e];
    int lo  = (e == 0) ? 0 : tgt[e - 1] + 1;
    for (int n = lo; n <= cur; ++n) row_ptr[n] = e;
    if (e == N_EDGES - 1) {
        for (int n = cur + 1; n <= N_NODES; ++n) row_ptr[n] = N_EDGES;
    }
}

// ---------------------------------------------------------------------------
// Gather-sum over fp16 rows, register-staged edge metadata.
// One wave per node; 4 edge-groups x 16 lanes; lane owns 4 features (8B).
// Per <=64-edge block: 2 coalesced exec-masked loads stage src/ev into lane
// registers (slots past end pre-zeroed: s=0,w=0 -> no bounds checks in loop).
// Hot loop per 8 edges: 4 shfl (bpermute) + 2 gathers + 8 v_fma_mix.
// 2-stage pipeline: chunk c+1's gathers issued before chunk c is consumed.
// ---------------------------------------------------------------------------
__global__ __launch_bounds__(256) void gather_sum_h(
    const half4v* __restrict__ xh,       // [N_NODES, 16] half4
    const float*  __restrict__ ev,
    const int*    __restrict__ src,
    const int*    __restrict__ row_ptr,
    float4*       __restrict__ out4)     // [N_NODES, 16] float4
{
    const int node = blockIdx.x * 4 + (threadIdx.x >> 6);
    if (node >= N_NODES) return;
    const int lane = threadIdx.x & 63;
    const int g    = lane >> 4;
    const int f    = lane & 15;

    const int start = row_ptr[node];
    const int end   = row_ptr[node + 1];

    float4 acc = make_float4(0.f, 0.f, 0.f, 0.f);

    for (int blk = start; blk < end; blk += 64) {
        const int blen = min(64, end - blk);

        // stage up to 64 edges' metadata into lane registers
        int   si = 0;
        float wi = 0.0f;
        if (lane < blen) {
            si = src[blk + lane];
            wi = ev[blk + lane];
        }
        const int nchunks = (blen + 7) >> 3;

        // prologue: chunk 0
        int   sa = __shfl(si, g,     64);
        int   sb = __shfl(si, g + 4, 64);
        float wa = __shfl(wi, g,     64);
        float wb = __shfl(wi, g + 4, 64);
        half4v xa = xh[sa * 16 + f];
        half4v xb = xh[sb * 16 + f];

        for (int c = 1; c < nchunks; ++c) {
            const int base = c * 8;
            // next chunk: distribute staged metadata, issue gathers
            const int   nsa = __shfl(si, base + g,     64);
            const int   nsb = __shfl(si, base + g + 4, 64);
            const float nwa = __shfl(wi, base + g,     64);
            const float nwb = __shfl(wi, base + g + 4, 64);
            const half4v nxa = xh[nsa * 16 + f];
            const half4v nxb = xh[nsb * 16 + f];

            // consume current chunk
            acc.x = fmaf(wa, (float)xa.x, acc.x);
            acc.y = fmaf(wa, (float)xa.y, acc.y);
            acc.z = fmaf(wa, (float)xa.z, acc.z);
            acc.w = fmaf(wa, (float)xa.w, acc.w);
            acc.x = fmaf(wb, (float)xb.x, acc.x);
            acc.y = fmaf(wb, (float)xb.y, acc.y);
            acc.z = fmaf(wb, (float)xb.z, acc.z);
            acc.w = fmaf(wb, (float)xb.w, acc.w);

            sa = nsa; sb = nsb; wa = nwa; wb = nwb; xa = nxa; xb = nxb;
        }

        // consume last chunk
        acc.x = fmaf(wa, (float)xa.x, acc.x);
        acc.y = fmaf(wa, (float)xa.y, acc.y);
        acc.z = fmaf(wa, (float)xa.z, acc.z);
        acc.w = fmaf(wa, (float)xa.w, acc.w);
        acc.x = fmaf(wb, (float)xb.x, acc.x);
        acc.y = fmaf(wb, (float)xb.y, acc.y);
        acc.z = fmaf(wb, (float)xb.z, acc.z);
        acc.w = fmaf(wb, (float)xb.w, acc.w);
    }

    // reduce the 4 edge-groups
    acc.x += __shfl_xor(acc.x, 16, 64);
    acc.y += __shfl_xor(acc.y, 16, 64);
    acc.z += __shfl_xor(acc.z, 16, 64);
    acc.w += __shfl_xor(acc.w, 16, 64);
    acc.x += __shfl_xor(acc.x, 32, 64);
    acc.y += __shfl_xor(acc.y, 32, 64);
    acc.z += __shfl_xor(acc.z, 32, 64);
    acc.w += __shfl_xor(acc.w, 32, 64);

    if (g == 0) out4[node * 16 + f] = acc;
}

// fp32 fallback gather (R3 structure) if ws can't hold xh
__global__ __launch_bounds__(256) void gather_sum_f32(
    const float4* __restrict__ x4,
    const float*  __restrict__ ev,
    const int*    __restrict__ src,
    const int*    __restrict__ row_ptr,
    float4*       __restrict__ out4)
{
    const int node = blockIdx.x * 4 + (threadIdx.x >> 6);
    if (node >= N_NODES) return;
    const int lane = threadIdx.x & 63;
    const int g    = lane >> 4;
    const int f    = lane & 15;

    const int start = row_ptr[node];
    const int end   = row_ptr[node + 1];

    float4 acc = make_float4(0.f, 0.f, 0.f, 0.f);
    if (start < end) {
        int  ea = start + g, eb = start + 4 + g;
        bool va = ea < end,  vb = eb < end;
        int  esa = va ? ea : start, esb = vb ? eb : start;
        float wa = va ? ev[esa] : 0.0f;
        float wb = vb ? ev[esb] : 0.0f;
        int   sa = src[esa];
        int   sb = src[esb];

        for (int e0 = start; e0 < end; e0 += 8) {
            const float4 xa = x4[sa * 16 + f];
            const float4 xb = x4[sb * 16 + f];
            const float cwa = wa, cwb = wb;
            {
                int  na = e0 + 8 + g, nb = e0 + 12 + g;
                bool vna = na < end,  vnb = nb < end;
                int  nsa = vna ? na : start, nsb = vnb ? nb : start;
                wa = vna ? ev[nsa] : 0.0f;
                wb = vnb ? ev[nsb] : 0.0f;
                sa = src[nsa];
                sb = src[nsb];
            }
            acc.x = fmaf(cwa, xa.x, acc.x);
            acc.y = fmaf(cwa, xa.y, acc.y);
            acc.z = fmaf(cwa, xa.z, acc.z);
            acc.w = fmaf(cwa, xa.w, acc.w);
            acc.x = fmaf(cwb, xb.x, acc.x);
            acc.y = fmaf(cwb, xb.y, acc.y);
            acc.z = fmaf(cwb, xb.z, acc.z);
            acc.w = fmaf(cwb, xb.w, acc.w);
        }
    }
    acc.x += __shfl_xor(acc.x, 16, 64);
    acc.y += __shfl_xor(acc.y, 16, 64);
    acc.z += __shfl_xor(acc.z, 16, 64);
    acc.w += __shfl_xor(acc.w, 16, 64);
    acc.x += __shfl_xor(acc.x, 32, 64);
    acc.y += __shfl_xor(acc.y, 32, 64);
    acc.z += __shfl_xor(acc.z, 32, 64);
    acc.w += __shfl_xor(acc.w, 32, 64);
    if (g == 0) out4[node * 16 + f] = acc;
}

extern "C" void kernel_launch(void* const* d_in, const int* in_sizes, int n_in,
                              void* d_out, int out_size, void* d_ws, size_t ws_size,
                              hipStream_t stream) {
    const float* x            = (const float*)d_in[0];
    const float* edge_values  = (const float*)d_in[1];
    const int*   target_index = (const int*)d_in[2];
    const int*   source_index = (const int*)d_in[3];
    float*       out          = (float*)d_out;

    const size_t rp_bytes = (size_t)(N_NODES + 1) * sizeof(int);
    const size_t xh_off   = (rp_bytes + 511) & ~(size_t)511;
    const size_t xh_bytes = (size_t)N_NODES * D_FEAT * sizeof(_Float16); // 12.8 MB
    const size_t need     = xh_off + xh_bytes;

    int* row_ptr = (int*)d_ws;

    if (ws_size >= need) {
        half4v* xh = (half4v*)((char*)d_ws + xh_off);
        const int conv_blocks = (N_NODES * 16 + 255) / 256;          // 6250
        const int rp_blocks   = (N_EDGES + 255) / 256;               // 6250
        prep_kernel<<<conv_blocks + rp_blocks, 256, 0, stream>>>(
            (const float4*)x, target_index, xh, row_ptr, conv_blocks);

        gather_sum_h<<<(N_NODES + 3) / 4, 256, 0, stream>>>(
            xh, edge_values, source_index, row_ptr, (float4*)out);
    } else {
        build_row_ptr<<<(N_EDGES + 255) / 256, 256, 0, stream>>>(target_index, row_ptr);
        gather_sum_f32<<<(N_NODES + 3) / 4, 256, 0, stream>>>(
            (const float4*)x, edge_values, source_index, row_ptr, (float4*)out);
    }
}

// Round 7
// 120.401 us; speedup vs baseline: 1.2086x; 1.0589x over previous
//
#include <hip/hip_runtime.h>
#include <hip/hip_fp16.h>

#define N_NODES 100000
#define N_EDGES 1600000
#define D_FEAT 64

typedef __attribute__((ext_vector_type(4))) _Float16 half4v;

// ---------------------------------------------------------------------------
// Prep (fused): part A converts x (fp32) -> xh (fp16, 128B rows);
//               part B builds CSR row_ptr from sorted target_index.
// ---------------------------------------------------------------------------
__global__ __launch_bounds__(256) void prep_kernel(
    const float4* __restrict__ x4,   // [N_NODES*16]
    const int*    __restrict__ tgt,  // [N_EDGES] sorted
    half4v*       __restrict__ xh,   // [N_NODES*16]
    int*          __restrict__ row_ptr,
    int conv_blocks)
{
    const int bid = blockIdx.x;
    if (bid < conv_blocks) {
        int i = bid * 256 + threadIdx.x;       // one float4 -> one half4
        if (i < N_NODES * 16) {
            float4 v = x4[i];
            half4v h;
            h.x = (_Float16)v.x; h.y = (_Float16)v.y;
            h.z = (_Float16)v.z; h.w = (_Float16)v.w;
            xh[i] = h;
        }
    } else {
        int e = (bid - conv_blocks) * 256 + threadIdx.x;
        if (e >= N_EDGES) return;
        int cur = tgt[e];
        int lo  = (e == 0) ? 0 : tgt[e - 1] + 1;
        for (int n = lo; n <= cur; ++n) row_ptr[n] = e;
        if (e == N_EDGES - 1) {
            for (int n = cur + 1; n <= N_NODES; ++n) row_ptr[n] = N_EDGES;
        }
    }
}

// Standalone row_ptr build (fallback path)
__global__ __launch_bounds__(256) void build_row_ptr(
    const int* __restrict__ tgt, int* __restrict__ row_ptr)
{
    int e = blockIdx.x * blockDim.x + threadIdx.x;
    if (e >= N_EDGES) return;
    int cur = tgt[e];
    int lo  = (e == 0) ? 0 : tgt[e - 1] + 1;
    for (int n = lo; n <= cur; ++n) row_ptr[n] = e;
    if (e == N_EDGES - 1) {
        for (int n = cur + 1; n <= N_NODES; ++n) row_ptr[n] = N_EDGES;
    }
}

// ---------------------------------------------------------------------------
// Gather-sum over fp16 rows: one 16-lane group owns one node end-to-end.
// No cross-group reduction, unconditional float4 store per group.
// Per 16-edge block: (src,ev) staged to LDS (1 ds_write_b64/lane), chunk loop
// reads group-uniform ds_read_b128 broadcasts (144B stride -> conflict-free),
// issues 4 gathers/chunk/group (16 edges in flight per wave), 2-deep pipeline.
// Slots past the node's degree are padded s=0,w=0 (harmless row-0 loads).
// ---------------------------------------------------------------------------
#define GROUPS_PER_BLOCK 16
#define LDS_STRIDE_B     144   // 16 slots * 8B + 16B pad (keeps b128 16B-aligned)

__global__ __launch_bounds__(256) void gather_sum_h(
    const half4v* __restrict__ xh,       // [N_NODES, 16] half4
    const float*  __restrict__ ev,
    const int*    __restrict__ src,
    const int*    __restrict__ row_ptr,
    float4*       __restrict__ out4)     // [N_NODES, 16] float4
{
    __shared__ char lds_raw[GROUPS_PER_BLOCK * LDS_STRIDE_B];

    const int tib  = threadIdx.x;
    const int gib  = tib >> 4;          // group within block: 0..15
    const int lane = tib & 15;          // lane within group
    const int node = blockIdx.x * GROUPS_PER_BLOCK + gib;
    if (node >= N_NODES) return;

    char* gbase = lds_raw + gib * LDS_STRIDE_B;

    const int start = row_ptr[node];
    const int end   = row_ptr[node + 1];

    float4 acc = make_float4(0.f, 0.f, 0.f, 0.f);

    for (int blk = start; blk < end; blk += 16) {
        const int bcnt = end - blk;          // >=1; clamp handled by padding

        // stage this block's (src, ev) pairs; pad unused slots with (0, 0.0f)
        int   s_ = 0; float w_ = 0.0f;
        if (lane < bcnt) { s_ = src[blk + lane]; w_ = ev[blk + lane]; }
        ((int2*)gbase)[lane] = make_int2(s_, __float_as_int(w_));

        const int nch = (min(bcnt, 16) + 3) >> 2;   // chunks of 4 edges

        // ---- chunk 0: meta broadcast + 4 gathers
        int4 m01 = ((const int4*)gbase)[0];   // s0,w0,s1,w1
        int4 m23 = ((const int4*)gbase)[1];   // s2,w2,s3,w3
        half4v x0 = xh[m01.x * 16 + lane];
        half4v x1 = xh[m01.z * 16 + lane];
        half4v x2 = xh[m23.x * 16 + lane];
        half4v x3 = xh[m23.z * 16 + lane];
        float w0 = __int_as_float(m01.y), w1 = __int_as_float(m01.w);
        float w2 = __int_as_float(m23.y), w3 = __int_as_float(m23.w);

        for (int c = 1; c < nch; ++c) {
            // next chunk: meta + gathers issued before consuming current
            int4 n01 = ((const int4*)gbase)[2 * c];
            int4 n23 = ((const int4*)gbase)[2 * c + 1];
            half4v nx0 = xh[n01.x * 16 + lane];
            half4v nx1 = xh[n01.z * 16 + lane];
            half4v nx2 = xh[n23.x * 16 + lane];
            half4v nx3 = xh[n23.z * 16 + lane];

            // consume current chunk
            acc.x = fmaf(w0, (float)x0.x, acc.x);
            acc.y = fmaf(w0, (float)x0.y, acc.y);
            acc.z = fmaf(w0, (float)x0.z, acc.z);
            acc.w = fmaf(w0, (float)x0.w, acc.w);
            acc.x = fmaf(w1, (float)x1.x, acc.x);
            acc.y = fmaf(w1, (float)x1.y, acc.y);
            acc.z = fmaf(w1, (float)x1.z, acc.z);
            acc.w = fmaf(w1, (float)x1.w, acc.w);
            acc.x = fmaf(w2, (float)x2.x, acc.x);
            acc.y = fmaf(w2, (float)x2.y, acc.y);
            acc.z = fmaf(w2, (float)x2.z, acc.z);
            acc.w = fmaf(w2, (float)x2.w, acc.w);
            acc.x = fmaf(w3, (float)x3.x, acc.x);
            acc.y = fmaf(w3, (float)x3.y, acc.y);
            acc.z = fmaf(w3, (float)x3.z, acc.z);
            acc.w = fmaf(w3, (float)x3.w, acc.w);

            x0 = nx0; x1 = nx1; x2 = nx2; x3 = nx3;
            w0 = __int_as_float(n01.y); w1 = __int_as_float(n01.w);
            w2 = __int_as_float(n23.y); w3 = __int_as_float(n23.w);
        }

        // consume final chunk
        acc.x = fmaf(w0, (float)x0.x, acc.x);
        acc.y = fmaf(w0, (float)x0.y, acc.y);
        acc.z = fmaf(w0, (float)x0.z, acc.z);
        acc.w = fmaf(w0, (float)x0.w, acc.w);
        acc.x = fmaf(w1, (float)x1.x, acc.x);
        acc.y = fmaf(w1, (float)x1.y, acc.y);
        acc.z = fmaf(w1, (float)x1.z, acc.z);
        acc.w = fmaf(w1, (float)x1.w, acc.w);
        acc.x = fmaf(w2, (float)x2.x, acc.x);
        acc.y = fmaf(w2, (float)x2.y, acc.y);
        acc.z = fmaf(w2, (float)x2.z, acc.z);
        acc.w = fmaf(w2, (float)x2.w, acc.w);
        acc.x = fmaf(w3, (float)x3.x, acc.x);
        acc.y = fmaf(w3, (float)x3.y, acc.y);
        acc.z = fmaf(w3, (float)x3.z, acc.z);
        acc.w = fmaf(w3, (float)x3.w, acc.w);
    }

    out4[node * 16 + lane] = acc;   // unconditional: empty nodes store 0
}

// fp32 fallback gather (R3 structure) if ws can't hold xh
__global__ __launch_bounds__(256) void gather_sum_f32(
    const float4* __restrict__ x4,
    const float*  __restrict__ ev,
    const int*    __restrict__ src,
    const int*    __restrict__ row_ptr,
    float4*       __restrict__ out4)
{
    const int node = blockIdx.x * 4 + (threadIdx.x >> 6);
    if (node >= N_NODES) return;
    const int lane = threadIdx.x & 63;
    const int g    = lane >> 4;
    const int f    = lane & 15;

    const int start = row_ptr[node];
    const int end   = row_ptr[node + 1];

    float4 acc = make_float4(0.f, 0.f, 0.f, 0.f);
    if (start < end) {
        int  ea = start + g, eb = start + 4 + g;
        bool va = ea < end,  vb = eb < end;
        int  esa = va ? ea : start, esb = vb ? eb : start;
        float wa = va ? ev[esa] : 0.0f;
        float wb = vb ? ev[esb] : 0.0f;
        int   sa = src[esa];
        int   sb = src[esb];

        for (int e0 = start; e0 < end; e0 += 8) {
            const float4 xa = x4[sa * 16 + f];
            const float4 xb = x4[sb * 16 + f];
            const float cwa = wa, cwb = wb;
            {
                int  na = e0 + 8 + g, nb = e0 + 12 + g;
                bool vna = na < end,  vnb = nb < end;
                int  nsa = vna ? na : start, nsb = vnb ? nb : start;
                wa = vna ? ev[nsa] : 0.0f;
                wb = vnb ? ev[nsb] : 0.0f;
                sa = src[nsa];
                sb = src[nsb];
            }
            acc.x = fmaf(cwa, xa.x, acc.x);
            acc.y = fmaf(cwa, xa.y, acc.y);
            acc.z = fmaf(cwa, xa.z, acc.z);
            acc.w = fmaf(cwa, xa.w, acc.w);
            acc.x = fmaf(cwb, xb.x, acc.x);
            acc.y = fmaf(cwb, xb.y, acc.y);
            acc.z = fmaf(cwb, xb.z, acc.z);
            acc.w = fmaf(cwb, xb.w, acc.w);
        }
    }
    acc.x += __shfl_xor(acc.x, 16, 64);
    acc.y += __shfl_xor(acc.y, 16, 64);
    acc.z += __shfl_xor(acc.z, 16, 64);
    acc.w += __shfl_xor(acc.w, 16, 64);
    acc.x += __shfl_xor(acc.x, 32, 64);
    acc.y += __shfl_xor(acc.y, 32, 64);
    acc.z += __shfl_xor(acc.z, 32, 64);
    acc.w += __shfl_xor(acc.w, 32, 64);
    if (g == 0) out4[node * 16 + f] = acc;
}

extern "C" void kernel_launch(void* const* d_in, const int* in_sizes, int n_in,
                              void* d_out, int out_size, void* d_ws, size_t ws_size,
                              hipStream_t stream) {
    const float* x            = (const float*)d_in[0];
    const float* edge_values  = (const float*)d_in[1];
    const int*   target_index = (const int*)d_in[2];
    const int*   source_index = (const int*)d_in[3];
    float*       out          = (float*)d_out;

    const size_t rp_bytes = (size_t)(N_NODES + 1) * sizeof(int);
    const size_t xh_off   = (rp_bytes + 511) & ~(size_t)511;
    const size_t xh_bytes = (size_t)N_NODES * D_FEAT * sizeof(_Float16); // 12.8 MB
    const size_t need     = xh_off + xh_bytes;

    int* row_ptr = (int*)d_ws;

    if (ws_size >= need) {
        half4v* xh = (half4v*)((char*)d_ws + xh_off);
        const int conv_blocks = (N_NODES * 16 + 255) / 256;          // 6250
        const int rp_blocks   = (N_EDGES + 255) / 256;               // 6250
        prep_kernel<<<conv_blocks + rp_blocks, 256, 0, stream>>>(
            (const float4*)x, target_index, xh, row_ptr, conv_blocks);

        const int n_blocks = (N_NODES + GROUPS_PER_BLOCK - 1) / GROUPS_PER_BLOCK;
        gather_sum_h<<<n_blocks, 256, 0, stream>>>(
            xh, edge_values, source_index, row_ptr, (float4*)out);
    } else {
        build_row_ptr<<<(N_EDGES + 255) / 256, 256, 0, stream>>>(target_index, row_ptr);
        gather_sum_f32<<<(N_NODES + 3) / 4, 256, 0, stream>>>(
            (const float4*)x, edge_values, source_index, row_ptr, (float4*)out);
    }
}